// Round 3
// baseline (63.343 us; speedup 1.0000x reference)
//
#include <hip/hip_runtime.h>

#define N_    32
#define CIN   128
#define H_    56
#define W_    56
#define HW_   (H_ * W_)
#define COUT  256
#define GROUPS 4
#define CPG   32      // in-channels per group
#define OPG   64      // out-channels per group
#define CDIM  64

#define TH     8              // output rows per block
#define HALO_R (TH + 2)       // 10
#define HALO_C (W_ + 2)       // 58
#define NPIX   (TH * W_)      // 448
#define NT     (NPIX / 16)    // 28 pixel tiles (7 per wave)
#define XPLANE (HALO_R * HALO_C)  // 580 halo pixels

typedef __bf16 bf16x8 __attribute__((ext_vector_type(8)));
typedef float  f32x4  __attribute__((ext_vector_type(4)));

// ---------- pre-kernel 1: ctx[n][oc] = bias[oc] + c[n,:] . cw[oc,:] ----------
__global__ void ctx_kernel(const float* __restrict__ c, const float* __restrict__ bias,
                           const float* __restrict__ cw, float* __restrict__ gctx) {
    const int n  = blockIdx.x;
    const int oc = threadIdx.x;
    const float* cn  = c  + n * CDIM;   // wave-uniform -> s_loads
    const float* cwo = cw + oc * CDIM;
    float s = bias[oc];
    #pragma unroll
    for (int d = 0; d < CDIM; ++d) s += cn[d] * cwo[d];
    gctx[n * COUT + oc] = s;
}

// ---------- pre-kernel 2: weight fp32 [oc][ic][3][3] -> bf16 [g][tap][oct][ocL][8] ----------
__global__ void wconv_kernel(const float* __restrict__ wgt, __bf16* __restrict__ wbf) {
    int j = blockIdx.x * 256 + threadIdx.x;       // output linear index, coalesced write
    int e   = j & 7;
    int r   = j >> 3;
    int ocL = r & 63;  r >>= 6;
    int o   = r & 3;   r >>= 2;                   // ic octet
    int tap = r % 9;
    int g   = r / 9;
    int ic  = o * 8 + e;
    wbf[j] = (__bf16)wgt[((g * OPG + ocL) * CPG + ic) * 9 + tap];
}

// ---------- main kernel ----------
__global__ __launch_bounds__(512, 4) void ctx_conv_kernel(
    const float* __restrict__ x, const __bf16* __restrict__ wbf,
    const float* __restrict__ gctx, float* __restrict__ out)
{
    // pixel-major: row = one halo pixel's 32 ic (64 B). b-frag = 16B aligned slice.
    __shared__ __align__(16) __bf16 x_lds[XPLANE][CPG];   // 37120 B

    const int ht  = blockIdx.x;   // 0..6  (8-row strip)
    const int g   = blockIdx.y;   // 0..3
    const int n   = blockIdx.z;   // 0..31
    const int tid = threadIdx.x;  // 0..511
    const int h0  = ht * TH;

    const int wv   = tid >> 6;       // 0..7
    const int lane = tid & 63;
    const int l15  = lane & 15;
    const int kh4  = lane >> 4;      // ic octet / D row group
    const int p2   = (wv & 1) * 2;   // oc-tile pair base (0 or 2)
    const int pq   = wv >> 1;        // pixel quarter (0..3)

    // ---- a-frags straight from global (L2-hot, pre-permuted) ----
    bf16x8 a[2][9];
    {
        const __bf16* wgb = wbf + (size_t)g * (9 * 4 * OPG * 8);
        #pragma unroll
        for (int i = 0; i < 2; ++i)
            #pragma unroll
            for (int tap = 0; tap < 9; ++tap)
                a[i][tap] = *(const bf16x8*)&wgb[(((tap * 4 + kh4) * OPG) + (p2 + i) * 16 + l15) * 8];
    }
    float ctxv[2][4];
    #pragma unroll
    for (int i = 0; i < 2; ++i)
        #pragma unroll
        for (int r = 0; r < 4; ++r)
            ctxv[i][r] = gctx[n * COUT + g * OPG + (p2 + i) * 16 + kh4 * 4 + r];

    // ---- stage x strip with zero halo: job = (halo pixel, ic octet), oct fastest ----
    {
        const float* xg = x + ((size_t)n * CIN + g * CPG) * HW_;
        for (int j = tid; j < 4 * XPLANE; j += 512) {
            int pix = j >> 2;
            int oct = j & 3;
            int hr = pix / HALO_C;
            int wc = pix - hr * HALO_C;
            int hg  = h0 - 1 + hr;
            int wg2 = wc - 1;
            bool valid = ((unsigned)hg < (unsigned)H_) && ((unsigned)wg2 < (unsigned)W_);
            const float* src = xg + (size_t)(oct * 8) * HW_ + hg * W_ + wg2;
            bf16x8 v;
            #pragma unroll
            for (int e = 0; e < 8; ++e)
                v[e] = (__bf16)(valid ? src[(size_t)e * HW_] : 0.f);
            *(bf16x8*)&x_lds[pix][oct * 8] = v;   // contiguous 16B, conflict-free
        }
    }
    __syncthreads();

    float* outb = out + ((size_t)n * COUT + g * OPG + p2 * 16 + kh4 * 4) * HW_ + h0 * W_;

    #pragma unroll 1
    for (int t = pq * 7; t < pq * 7 + 7; ++t) {
        int p  = t * 16 + l15;           // pixel within strip (B col & D col)
        int pr = p / W_;
        int pc = p - pr * W_;
        f32x4 acc0 = {0.f, 0.f, 0.f, 0.f};
        f32x4 acc1 = {0.f, 0.f, 0.f, 0.f};
        #pragma unroll
        for (int kh = 0; kh < 3; ++kh) {
            #pragma unroll
            for (int kw = 0; kw < 3; ++kw) {
                const bf16x8 b = *(const bf16x8*)&x_lds[(pr + kh) * HALO_C + (pc + kw)][kh4 * 8];
                acc0 = __builtin_amdgcn_mfma_f32_16x16x32_bf16(a[0][kh * 3 + kw], b, acc0, 0, 0, 0);
                acc1 = __builtin_amdgcn_mfma_f32_16x16x32_bf16(a[1][kh * 3 + kw], b, acc1, 0, 0, 0);
            }
        }
        #pragma unroll
        for (int r = 0; r < 4; ++r)
            outb[(size_t)r * HW_ + p] = acc0[r] + ctxv[0][r];
        #pragma unroll
        for (int r = 0; r < 4; ++r)
            outb[(size_t)(16 + r) * HW_ + p] = acc1[r] + ctxv[1][r];
    }
}

extern "C" void kernel_launch(void* const* d_in, const int* in_sizes, int n_in,
                              void* d_out, int out_size, void* d_ws, size_t ws_size,
                              hipStream_t stream) {
    const float* x    = (const float*)d_in[0];
    const float* c    = (const float*)d_in[1];
    const float* wgt  = (const float*)d_in[2];
    const float* bias = (const float*)d_in[3];
    const float* cw   = (const float*)d_in[4];
    float* out = (float*)d_out;

    float*  gctx = (float*)d_ws;                          // 32 KB
    __bf16* wbf  = (__bf16*)((char*)d_ws + 32768);        // 144 KB

    ctx_kernel<<<dim3(N_), 256, 0, stream>>>(c, bias, cw, gctx);
    wconv_kernel<<<dim3((COUT * CPG * 9) / 256), 256, 0, stream>>>(wgt, wbf);

    dim3 grid(H_ / TH, GROUPS, N_);   // (7, 4, 32)
    ctx_conv_kernel<<<grid, 512, 0, stream>>>(x, wbf, gctx, out);
}